// Round 9
// baseline (237.564 us; speedup 1.0000x reference)
//
#include <hip/hip_runtime.h>
#include <hip/hip_bf16.h>

// Problem constants (from reference)
#define HD 64
#define VOCAB 64
#define SEQ 48

// Tables are bf16, row = 64 bf16 = 128 B = 8 chunks of 16 B.
// Chunk c of row r is stored at chunk position (c ^ (r & 7)) — XOR swizzle so a
// wave's 64 b128 reads (random rows) spread uniformly over all 8 bank groups.
// Same-row same-chunk lanes hit the same address -> LDS broadcast (free).
#define TROWS 128            // 64 T1 rows then 64 T2 rows
#define TELEMS (TROWS * 64)  // ushort count = 8192 -> 16384 B

using frag_ab = __attribute__((ext_vector_type(8))) short;   // 8 bf16
using frag_cd = __attribute__((ext_vector_type(4))) float;   // 4 fp32
typedef __attribute__((ext_vector_type(4))) float floatx4;
typedef __attribute__((ext_vector_type(4))) unsigned int uintx4;

static __device__ inline unsigned short f2bf(float f) {
  // round-to-nearest-even fp32 -> bf16 (used in table build only)
  unsigned u = __float_as_uint(f);
  unsigned r = (u + 0x7fffu + ((u >> 16) & 1u)) >> 16;
  return (unsigned short)r;
}
static __device__ inline float blo(unsigned w) { return __uint_as_float(w << 16); }
static __device__ inline float bhi(unsigned w) { return __uint_as_float(w & 0xffff0000u); }
static __device__ inline short cvt_bf(float f) {
  // plain scalar cast: compiler fuses adjacent pairs into v_cvt_pk_bf16_f32 (RNE)
  return (short)__bfloat16_as_short(__float2bfloat16(f));
}

// Kernel A: build fused first-layer tables in workspace (bf16, chunk-swizzled).
// T1[v][j] = sum_k embed[v][k]*W1[j][k] + b1[j]          (query half)
// T2[v][j] = 0.25 * sum_k embed[v][k]*W1[j][64+k]        (memory half, mean folded)
__global__ void build_tables(const float* __restrict__ embed,
                             const float* __restrict__ W1,
                             const float* __restrict__ b1,
                             unsigned short* __restrict__ T) {
  int v = blockIdx.x;    // 0..63
  int j = threadIdx.x;   // 0..63
  const float* e = embed + v * HD;
  const float* w1r = W1 + j * (2 * HD);
  float s1 = 0.f, s2 = 0.f;
  for (int k = 0; k < HD; ++k) {
    float ev = e[k];              // uniform per block -> scalar loads
    s1 += ev * w1r[k];
    s2 += ev * w1r[HD + k];
  }
  // swizzled element position within a row: chunk (j>>3) -> (j>>3) ^ (row&7)
  int c1 = ((j >> 3) ^ (v & 7)) * 8 + (j & 7);
  T[v * 64 + c1] = f2bf(s1 + b1[j]);
  int r2 = 64 + v;                       // (r2 & 7) == (v & 7)
  T[r2 * 64 + c1] = f2bf(0.25f * s2);
}

// Kernel B v9: identical to v8 except the 4 output dwordx4 stores are
// NONTEMPORAL. Rationale: each 64B line is fully covered by 4 lanes of ONE
// store instruction (quad 0..3, same m, same t) -> nt write-combines into
// full-line HBM writes with no RMW (unlike R2's scattered dword nt stores)
// and no L2 allocation, so the store stream stops contending with L2
// writeback of the harness's 512MiB poison fill.
__global__ __launch_bounds__(256, 4) void lru_main(
    const int* __restrict__ seqs, const int* __restrict__ qtok,
    const float* __restrict__ W2, const float* __restrict__ b2,
    const unsigned short* __restrict__ T, float* __restrict__ out, int nbatch) {
  __shared__ __align__(16) unsigned short sT[TELEMS];   // 16384 B

  const int lane = threadIdx.x & 63;
  const int quad = lane >> 4;
  const int m    = lane & 15;
  const int k0   = quad * 8;

  const int wave = blockIdx.x * (blockDim.x >> 6) + (threadIdx.x >> 6);
  const int nw   = gridDim.x * (blockDim.x >> 6);
  const int R    = nbatch * 16;             // total rows
  const int ngroup = (nbatch + 3) >> 2;     // groups of 4 batches (64 rows)

  // ---- issue first group's token loads NOW; they complete under staging ----
  int g = wave;
  int q_cur = 0, a_cur = 0;
  int4 b_cur = make_int4(0, 0, 0, 0);
  if (g < ngroup) {
    int r = g * 64 + lane; if (r >= R) r = R - 1;
    q_cur = qtok[r];                          // 256B fully coalesced per wave
    const int* sp = seqs + (size_t)r * SEQ;
    a_cur = sp[43];                           // col 43
    b_cur = *(const int4*)(sp + 44);          // cols 44,45,46,(47 unused); 16B-aligned
  }

  // cooperative stage of the table (16 KB contiguous)
  {
    const floatx4* src = (const floatx4*)T;
    floatx4* dst = (floatx4*)sT;
    for (int i = threadIdx.x; i < TELEMS / 8; i += blockDim.x) dst[i] = src[i];
  }
  __syncthreads();

  // W2 fragments (A-operand of the transposed MFMA):
  // A[am=lane&15][k = s*32 + quad*8 + j] = W2[t*16+am][k]
  frag_ab bf[4][2];
  for (int t = 0; t < 4; ++t)
    for (int s = 0; s < 2; ++s) {
      const float* w2r = W2 + (t * 16 + m) * HD + s * 32 + k0;
      const floatx4 v0 = *(const floatx4*)(w2r);
      const floatx4 v1 = *(const floatx4*)(w2r + 4);
      for (int j = 0; j < 4; ++j) {
        bf[t][s][j]     = cvt_bf(v0[j]);
        bf[t][s][4 + j] = cvt_bf(v1[j]);
      }
    }
  // bias pre-loaded into C-init: lane (quad,m) owns out cols t*16+quad*4 .. +3
  frag_cd bini[4];
  for (int t = 0; t < 4; ++t)
    bini[t] = *(const floatx4*)(b2 + t * 16 + quad * 4);

  for (; g < ngroup; g += nw) {
    // ---- prefetch NEXT group's tokens (overlaps with this group's compute) ----
    const int gn = g + nw;
    int q_nxt = 0, a_nxt = 0;
    int4 b_nxt = make_int4(0, 0, 0, 0);
    if (gn < ngroup) {
      int r = gn * 64 + lane; if (r >= R) r = R - 1;
      q_nxt = qtok[r];
      const int* sp = seqs + (size_t)r * SEQ;
      a_nxt = sp[43];
      b_nxt = *(const int4*)(sp + 44);
    }

#pragma unroll
    for (int it = 0; it < 4; ++it) {
      const int b = g * 4 + it;
      if (b >= nbatch) break;                 // wave-uniform guard

      // tokens for row it*16+m live in lane it*16+m
      const int srcl = it * 16 + m;
      const int q  = __shfl(q_cur, srcl);
      const int t0 = __shfl(a_cur, srcl) + 64;
      const int t1 = __shfl(b_cur.x, srcl) + 64;
      const int t2 = __shfl(b_cur.y, srcl) + 64;
      const int t3 = __shfl(b_cur.z, srcl) + 64;

      // ---- issue ALL 10 table reads first: 10 b128 in flight in parallel ----
      // chunk for (row, s) sits at ushort offset row*64 + ((s*4+quad)^(row&7))*8
      uintx4 w0, w1, w2, w3, w4, w5, w6, w7, w8, w9;
      w0 = *(const uintx4*)(sT + q  * 64 + (((0 + quad) ^ (q  & 7)) << 3));
      w1 = *(const uintx4*)(sT + q  * 64 + (((4 + quad) ^ (q  & 7)) << 3));
      w2 = *(const uintx4*)(sT + t0 * 64 + (((0 + quad) ^ (t0 & 7)) << 3));
      w3 = *(const uintx4*)(sT + t0 * 64 + (((4 + quad) ^ (t0 & 7)) << 3));
      w4 = *(const uintx4*)(sT + t1 * 64 + (((0 + quad) ^ (t1 & 7)) << 3));
      w5 = *(const uintx4*)(sT + t1 * 64 + (((4 + quad) ^ (t1 & 7)) << 3));
      w6 = *(const uintx4*)(sT + t2 * 64 + (((0 + quad) ^ (t2 & 7)) << 3));
      w7 = *(const uintx4*)(sT + t2 * 64 + (((4 + quad) ^ (t2 & 7)) << 3));
      w8 = *(const uintx4*)(sT + t3 * 64 + (((0 + quad) ^ (t3 & 7)) << 3));
      w9 = *(const uintx4*)(sT + t3 * 64 + (((4 + quad) ^ (t3 & 7)) << 3));

      // ---- unpack + 5-way sum ----
      float s0[8], s1[8];
#pragma unroll
      for (int i = 0; i < 4; ++i) {
        s0[2 * i]     = blo(w0[i]) + blo(w2[i]) + blo(w4[i]) + blo(w6[i]) + blo(w8[i]);
        s0[2 * i + 1] = bhi(w0[i]) + bhi(w2[i]) + bhi(w4[i]) + bhi(w6[i]) + bhi(w8[i]);
        s1[2 * i]     = blo(w1[i]) + blo(w3[i]) + blo(w5[i]) + blo(w7[i]) + blo(w9[i]);
        s1[2 * i + 1] = bhi(w1[i]) + bhi(w3[i]) + bhi(w5[i]) + bhi(w7[i]) + bhi(w9[i]);
      }

      // ---- relu + bf16 pack into MFMA B-fragments (cvt_pk fusion) ----
      frag_ab a0, a1;
#pragma unroll
      for (int i = 0; i < 8; ++i) {
        a0[i] = cvt_bf(fmaxf(s0[i], 0.f));
        a1[i] = cvt_bf(fmaxf(s1[i], 0.f));
      }

      // Transposed product: D[am][bn] = sum_k W2[t*16+am][k] * h[bn][k]
      // Lane (quad,m): D rows am=quad*4+p (out cols), col bn=m (batch row).
      frag_cd acc[4];
      for (int t = 0; t < 4; ++t) {
        acc[t] = bini[t];
        acc[t] = __builtin_amdgcn_mfma_f32_16x16x32_bf16(bf[t][0], a0, acc[t], 0, 0, 0);
        acc[t] = __builtin_amdgcn_mfma_f32_16x16x32_bf16(bf[t][1], a1, acc[t], 0, 0, 0);
      }

      // Store: lane (quad,m) writes out[rb+m][t*16+quad*4 .. +3] as dwordx4.
      // Nontemporal: each 64B line is covered by quads 0..3 of ONE instruction
      // -> full-line nt write-combine, no RMW, no L2 allocation.
      float* orow = out + ((size_t)(b * 16) + m) * HD + quad * 4;
      for (int t = 0; t < 4; ++t)
        __builtin_nontemporal_store(acc[t], (floatx4*)(orow + t * 16));
    }

    q_cur = q_nxt; a_cur = a_nxt; b_cur = b_nxt;
  }
}

extern "C" void kernel_launch(void* const* d_in, const int* in_sizes, int n_in,
                              void* d_out, int out_size, void* d_ws, size_t ws_size,
                              hipStream_t stream) {
  const int*   seqs  = (const int*)d_in[0];
  const int*   qtok  = (const int*)d_in[1];
  const float* embed = (const float*)d_in[2];
  const float* W1    = (const float*)d_in[3];
  const float* b1    = (const float*)d_in[4];
  const float* W2    = (const float*)d_in[5];
  const float* b2    = (const float*)d_in[6];
  float* out = (float*)d_out;
  unsigned short* T = (unsigned short*)d_ws;   // 8192 ushort = 16384 B

  const int B = in_sizes[1];        // number of rows (524288)
  const int nbatch = B / 16;

  build_tables<<<VOCAB, HD, 0, stream>>>(embed, W1, b1, T);
  lru_main<<<1024, 256, 0, stream>>>(seqs, qtok, W2, b2, T, out, nbatch);
}

// Round 10
// 226.632 us; speedup vs baseline: 1.0482x; 1.0482x over previous
//
#include <hip/hip_runtime.h>
#include <hip/hip_bf16.h>

// Problem constants (from reference)
#define HD 64
#define VOCAB 64
#define SEQ 48

// Tables are bf16, row = 64 bf16 = 128 B = 8 chunks of 16 B.
// Chunk c of row r is stored at chunk position (c ^ (r & 7)) — XOR swizzle so a
// wave's 64 b128 reads (random rows) spread uniformly over all 8 bank groups.
// Same-row same-chunk lanes hit the same address -> LDS broadcast (free).
#define TROWS 128            // 64 T1 rows then 64 T2 rows
#define TELEMS (TROWS * 64)  // ushort count = 8192 -> 16384 B

using frag_ab = __attribute__((ext_vector_type(8))) short;   // 8 bf16
using frag_cd = __attribute__((ext_vector_type(4))) float;   // 4 fp32
typedef __attribute__((ext_vector_type(4))) float floatx4;
typedef __attribute__((ext_vector_type(4))) unsigned int uintx4;

static __device__ inline unsigned short f2bf(float f) {
  // round-to-nearest-even fp32 -> bf16 (used in table build only)
  unsigned u = __float_as_uint(f);
  unsigned r = (u + 0x7fffu + ((u >> 16) & 1u)) >> 16;
  return (unsigned short)r;
}
static __device__ inline float blo(unsigned w) { return __uint_as_float(w << 16); }
static __device__ inline float bhi(unsigned w) { return __uint_as_float(w & 0xffff0000u); }
static __device__ inline short cvt_bf(float f) {
  // plain scalar cast: compiler fuses adjacent pairs into v_cvt_pk_bf16_f32 (RNE)
  return (short)__bfloat16_as_short(__float2bfloat16(f));
}

// Kernel A: build fused first-layer tables in workspace (bf16, chunk-swizzled).
// T1[v][j] = sum_k embed[v][k]*W1[j][k] + b1[j]          (query half)
// T2[v][j] = 0.25 * sum_k embed[v][k]*W1[j][64+k]        (memory half, mean folded)
__global__ void build_tables(const float* __restrict__ embed,
                             const float* __restrict__ W1,
                             const float* __restrict__ b1,
                             unsigned short* __restrict__ T) {
  int v = blockIdx.x;    // 0..63
  int j = threadIdx.x;   // 0..63
  const float* e = embed + v * HD;
  const float* w1r = W1 + j * (2 * HD);
  float s1 = 0.f, s2 = 0.f;
  for (int k = 0; k < HD; ++k) {
    float ev = e[k];              // uniform per block -> scalar loads
    s1 += ev * w1r[k];
    s2 += ev * w1r[HD + k];
  }
  // swizzled element position within a row: chunk (j>>3) -> (j>>3) ^ (row&7)
  int c1 = ((j >> 3) ^ (v & 7)) * 8 + (j & 7);
  T[v * 64 + c1] = f2bf(s1 + b1[j]);
  int r2 = 64 + v;                       // (r2 & 7) == (v & 7)
  T[r2 * 64 + c1] = f2bf(0.25f * s2);
}

// Kernel B v10 == v8 (the session best, 227.4 us). R9 proved nt stores cost
// +10 us even at full-line coverage -> plain dwordx4 stores through L2 are
// the optimal store path on gfx950 for this write-once stream.
//  - all 10 ds_read_b128 issued before any consumption (parallel LDS latency;
//    peak ~110 VGPR, allowed by (256,4)'s 128 cap — do NOT tighten bounds)
//  - bf16 pack via scalar __float2bfloat16 casts -> v_cvt_pk_bf16_f32 fusion
//  - transposed MFMA (W2 as A-operand) so each lane owns 4 consecutive
//    output floats -> coalesced dwordx4 stores, zero write amplification
__global__ __launch_bounds__(256, 4) void lru_main(
    const int* __restrict__ seqs, const int* __restrict__ qtok,
    const float* __restrict__ W2, const float* __restrict__ b2,
    const unsigned short* __restrict__ T, float* __restrict__ out, int nbatch) {
  __shared__ __align__(16) unsigned short sT[TELEMS];   // 16384 B

  const int lane = threadIdx.x & 63;
  const int quad = lane >> 4;
  const int m    = lane & 15;
  const int k0   = quad * 8;

  const int wave = blockIdx.x * (blockDim.x >> 6) + (threadIdx.x >> 6);
  const int nw   = gridDim.x * (blockDim.x >> 6);
  const int R    = nbatch * 16;             // total rows
  const int ngroup = (nbatch + 3) >> 2;     // groups of 4 batches (64 rows)

  // ---- issue first group's token loads NOW; they complete under staging ----
  int g = wave;
  int q_cur = 0, a_cur = 0;
  int4 b_cur = make_int4(0, 0, 0, 0);
  if (g < ngroup) {
    int r = g * 64 + lane; if (r >= R) r = R - 1;
    q_cur = qtok[r];                          // 256B fully coalesced per wave
    const int* sp = seqs + (size_t)r * SEQ;
    a_cur = sp[43];                           // col 43
    b_cur = *(const int4*)(sp + 44);          // cols 44,45,46,(47 unused); 16B-aligned
  }

  // cooperative stage of the table (16 KB contiguous)
  {
    const floatx4* src = (const floatx4*)T;
    floatx4* dst = (floatx4*)sT;
    for (int i = threadIdx.x; i < TELEMS / 8; i += blockDim.x) dst[i] = src[i];
  }
  __syncthreads();

  // W2 fragments (A-operand of the transposed MFMA):
  // A[am=lane&15][k = s*32 + quad*8 + j] = W2[t*16+am][k]
  frag_ab bf[4][2];
  for (int t = 0; t < 4; ++t)
    for (int s = 0; s < 2; ++s) {
      const float* w2r = W2 + (t * 16 + m) * HD + s * 32 + k0;
      const floatx4 v0 = *(const floatx4*)(w2r);
      const floatx4 v1 = *(const floatx4*)(w2r + 4);
      for (int j = 0; j < 4; ++j) {
        bf[t][s][j]     = cvt_bf(v0[j]);
        bf[t][s][4 + j] = cvt_bf(v1[j]);
      }
    }
  // bias pre-loaded into C-init: lane (quad,m) owns out cols t*16+quad*4 .. +3
  frag_cd bini[4];
  for (int t = 0; t < 4; ++t)
    bini[t] = *(const floatx4*)(b2 + t * 16 + quad * 4);

  for (; g < ngroup; g += nw) {
    // ---- prefetch NEXT group's tokens (overlaps with this group's compute) ----
    const int gn = g + nw;
    int q_nxt = 0, a_nxt = 0;
    int4 b_nxt = make_int4(0, 0, 0, 0);
    if (gn < ngroup) {
      int r = gn * 64 + lane; if (r >= R) r = R - 1;
      q_nxt = qtok[r];
      const int* sp = seqs + (size_t)r * SEQ;
      a_nxt = sp[43];
      b_nxt = *(const int4*)(sp + 44);
    }

#pragma unroll
    for (int it = 0; it < 4; ++it) {
      const int b = g * 4 + it;
      if (b >= nbatch) break;                 // wave-uniform guard

      // tokens for row it*16+m live in lane it*16+m
      const int srcl = it * 16 + m;
      const int q  = __shfl(q_cur, srcl);
      const int t0 = __shfl(a_cur, srcl) + 64;
      const int t1 = __shfl(b_cur.x, srcl) + 64;
      const int t2 = __shfl(b_cur.y, srcl) + 64;
      const int t3 = __shfl(b_cur.z, srcl) + 64;

      // ---- issue ALL 10 table reads first: 10 b128 in flight in parallel ----
      // chunk for (row, s) sits at ushort offset row*64 + ((s*4+quad)^(row&7))*8
      uintx4 w0, w1, w2, w3, w4, w5, w6, w7, w8, w9;
      w0 = *(const uintx4*)(sT + q  * 64 + (((0 + quad) ^ (q  & 7)) << 3));
      w1 = *(const uintx4*)(sT + q  * 64 + (((4 + quad) ^ (q  & 7)) << 3));
      w2 = *(const uintx4*)(sT + t0 * 64 + (((0 + quad) ^ (t0 & 7)) << 3));
      w3 = *(const uintx4*)(sT + t0 * 64 + (((4 + quad) ^ (t0 & 7)) << 3));
      w4 = *(const uintx4*)(sT + t1 * 64 + (((0 + quad) ^ (t1 & 7)) << 3));
      w5 = *(const uintx4*)(sT + t1 * 64 + (((4 + quad) ^ (t1 & 7)) << 3));
      w6 = *(const uintx4*)(sT + t2 * 64 + (((0 + quad) ^ (t2 & 7)) << 3));
      w7 = *(const uintx4*)(sT + t2 * 64 + (((4 + quad) ^ (t2 & 7)) << 3));
      w8 = *(const uintx4*)(sT + t3 * 64 + (((0 + quad) ^ (t3 & 7)) << 3));
      w9 = *(const uintx4*)(sT + t3 * 64 + (((4 + quad) ^ (t3 & 7)) << 3));

      // ---- unpack + 5-way sum ----
      float s0[8], s1[8];
#pragma unroll
      for (int i = 0; i < 4; ++i) {
        s0[2 * i]     = blo(w0[i]) + blo(w2[i]) + blo(w4[i]) + blo(w6[i]) + blo(w8[i]);
        s0[2 * i + 1] = bhi(w0[i]) + bhi(w2[i]) + bhi(w4[i]) + bhi(w6[i]) + bhi(w8[i]);
        s1[2 * i]     = blo(w1[i]) + blo(w3[i]) + blo(w5[i]) + blo(w7[i]) + blo(w9[i]);
        s1[2 * i + 1] = bhi(w1[i]) + bhi(w3[i]) + bhi(w5[i]) + bhi(w7[i]) + bhi(w9[i]);
      }

      // ---- relu + bf16 pack into MFMA B-fragments (cvt_pk fusion) ----
      frag_ab a0, a1;
#pragma unroll
      for (int i = 0; i < 8; ++i) {
        a0[i] = cvt_bf(fmaxf(s0[i], 0.f));
        a1[i] = cvt_bf(fmaxf(s1[i], 0.f));
      }

      // Transposed product: D[am][bn] = sum_k W2[t*16+am][k] * h[bn][k]
      // Lane (quad,m): D rows am=quad*4+p (out cols), col bn=m (batch row).
      frag_cd acc[4];
      for (int t = 0; t < 4; ++t) {
        acc[t] = bini[t];
        acc[t] = __builtin_amdgcn_mfma_f32_16x16x32_bf16(bf[t][0], a0, acc[t], 0, 0, 0);
        acc[t] = __builtin_amdgcn_mfma_f32_16x16x32_bf16(bf[t][1], a1, acc[t], 0, 0, 0);
      }

      // Store: lane (quad,m) writes out[rb+m][t*16+quad*4 .. +3] as dwordx4
      // through L2 (plain stores; R9 measured nt = +10 us, do NOT re-add).
      float* orow = out + ((size_t)(b * 16) + m) * HD + quad * 4;
      for (int t = 0; t < 4; ++t)
        *(floatx4*)(orow + t * 16) = acc[t];
    }

    q_cur = q_nxt; a_cur = a_nxt; b_cur = b_nxt;
  }
}

extern "C" void kernel_launch(void* const* d_in, const int* in_sizes, int n_in,
                              void* d_out, int out_size, void* d_ws, size_t ws_size,
                              hipStream_t stream) {
  const int*   seqs  = (const int*)d_in[0];
  const int*   qtok  = (const int*)d_in[1];
  const float* embed = (const float*)d_in[2];
  const float* W1    = (const float*)d_in[3];
  const float* b1    = (const float*)d_in[4];
  const float* W2    = (const float*)d_in[5];
  const float* b2    = (const float*)d_in[6];
  float* out = (float*)d_out;
  unsigned short* T = (unsigned short*)d_ws;   // 8192 ushort = 16384 B

  const int B = in_sizes[1];        // number of rows (524288)
  const int nbatch = B / 16;

  build_tables<<<VOCAB, HD, 0, stream>>>(embed, W1, b1, T);
  lru_main<<<1024, 256, 0, stream>>>(seqs, qtok, W2, b2, T, out, nbatch);
}